// Round 1
// baseline (5827.206 us; speedup 1.0000x reference)
//
#include <hip/hip_runtime.h>

#define BATCH 4
#define SEQ 2048
#define BL (BATCH*SEQ)          // 8192 rows
#define DMODEL 1024
#define DINNER 2048
#define HEADDIM 64
#define NHEADS 32
#define DSTATE 128
#define CONVDIM 2304            // D_INNER + 2*D_STATE
#define DINPROJ 4384            // 2*D_INNER + 2*D_STATE + NHEADS
#define NPAD1 4480              // DINPROJ padded to multiple of 128
#define NBLOCKS 4
#define NLABEL 1000
#define EPSF 1e-5f

typedef __attribute__((ext_vector_type(8))) short short8;
typedef __attribute__((ext_vector_type(4))) float f32x4;
typedef __attribute__((ext_vector_type(4))) unsigned short us4;

__device__ __forceinline__ unsigned short f2bf(float f){
  unsigned int u = __float_as_uint(f);
  u += 0x7fffu + ((u >> 16) & 1u);   // RNE
  return (unsigned short)(u >> 16);
}
__device__ __forceinline__ float siluf_(float x){ return x / (1.f + expf(-x)); }

// ---------------- embedding gather ----------------
__global__ __launch_bounds__(256) void k_embed(const int* __restrict__ tok,
                                               const float* __restrict__ emb,
                                               float* __restrict__ x){
  int i = blockIdx.x*256 + threadIdx.x;         // over BL * (DMODEL/4)
  int row = i >> 8;
  int c4 = (i & 255) << 2;
  float4 v = *reinterpret_cast<const float4*>(emb + (size_t)tok[row]*DMODEL + c4);
  *reinterpret_cast<float4*>(x + (size_t)row*DMODEL + c4) = v;
}

// ---------------- layernorm -> bf16 ----------------
__global__ __launch_bounds__(256) void k_ln(const float* __restrict__ x,
                                            const float* __restrict__ w,
                                            const float* __restrict__ b,
                                            unsigned short* __restrict__ out){
  int row = blockIdx.x*4 + (threadIdx.x >> 6);
  int lane = threadIdx.x & 63;
  const float* xr = x + (size_t)row*DMODEL;
  float4 v[4];
  float s = 0.f;
  #pragma unroll
  for (int j=0;j<4;++j){
    v[j] = *reinterpret_cast<const float4*>(xr + (j*64+lane)*4);
    s += v[j].x + v[j].y + v[j].z + v[j].w;
  }
  #pragma unroll
  for (int o=1;o<64;o<<=1) s += __shfl_xor(s, o);
  float mu = s * (1.f/DMODEL);
  float s2 = 0.f;
  #pragma unroll
  for (int j=0;j<4;++j){
    v[j].x -= mu; v[j].y -= mu; v[j].z -= mu; v[j].w -= mu;
    s2 += v[j].x*v[j].x + v[j].y*v[j].y + v[j].z*v[j].z + v[j].w*v[j].w;
  }
  #pragma unroll
  for (int o=1;o<64;o<<=1) s2 += __shfl_xor(s2, o);
  float rstd = rsqrtf(s2*(1.f/DMODEL) + EPSF);
  unsigned short* orow = out + (size_t)row*DMODEL;
  #pragma unroll
  for (int j=0;j<4;++j){
    int c = (j*64+lane)*4;
    float4 wv = *reinterpret_cast<const float4*>(w + c);
    float4 bv = *reinterpret_cast<const float4*>(b + c);
    us4 uu;
    uu.x = f2bf(v[j].x*rstd*wv.x + bv.x);
    uu.y = f2bf(v[j].y*rstd*wv.y + bv.y);
    uu.z = f2bf(v[j].z*rstd*wv.z + bv.z);
    uu.w = f2bf(v[j].w*rstd*wv.w + bv.w);
    *reinterpret_cast<us4*>(orow + c) = uu;
  }
}

// ---------------- f32 -> bf16 convert with zero row padding ----------------
__global__ __launch_bounds__(256) void k_cvt_pad(const float* __restrict__ src,
                                                 unsigned short* __restrict__ dst,
                                                 int nsrc_rows, int kshift, int total4){
  int i = blockIdx.x*256 + threadIdx.x;
  if (i >= total4) return;
  int e0 = i << 2;
  int row = e0 >> kshift;
  us4 uu;
  if (row < nsrc_rows){
    float4 v = *reinterpret_cast<const float4*>(src + e0);
    uu.x = f2bf(v.x); uu.y = f2bf(v.y); uu.z = f2bf(v.z); uu.w = f2bf(v.w);
  } else {
    uu.x = 0; uu.y = 0; uu.z = 0; uu.w = 0;
  }
  *reinterpret_cast<us4*>(dst + e0) = uu;
}

// ---------------- bf16 GEMM: C[M,N](f32) = A[M,K] * B[N,K]^T (+resid)(+bias) ----------------
// m97 structure: 128x128 tile, BK=64, 4 waves, global_load_lds(16B), mfma 16x16x32 bf16.
__global__ __launch_bounds__(256) void k_gemm_bt(
    const unsigned short* __restrict__ A,
    const unsigned short* __restrict__ B,
    float* __restrict__ C,
    const float* __restrict__ resid,
    const float* __restrict__ bias,
    int K, int ldc, int n_limit)
{
  __shared__ __align__(16) unsigned short smA[128*64];
  __shared__ __align__(16) unsigned short smB[128*64];
  const int tid  = threadIdx.x;
  const int lane = tid & 63;
  const int wave = tid >> 6;
  const int m0 = blockIdx.y * 128;
  const int n0 = blockIdx.x * 128;
  const int wm = (wave >> 1) * 64;
  const int wn = (wave & 1) * 64;
  const int srow = lane >> 3;             // row within 8-row staging chunk
  const int scol = (lane & 7) * 8;        // k-element offset within row
  const int frow = lane & 15;             // MFMA fragment row (m or n)
  const int fk   = (lane >> 4) * 8;       // MFMA fragment k offset

  f32x4 acc[4][4];
  #pragma unroll
  for (int i=0;i<4;++i)
    #pragma unroll
    for (int j=0;j<4;++j)
      acc[i][j] = (f32x4){0.f,0.f,0.f,0.f};

  for (int kt = 0; kt < K; kt += 64){
    #pragma unroll
    for (int i=0;i<4;++i){
      int c = wave*4 + i;                 // 16 chunks of 8 rows x 64 k
      int row = c*8 + srow;
      const unsigned short* gA = A + (size_t)(m0 + row)*K + kt + scol;
      const unsigned short* gB = B + (size_t)(n0 + row)*K + kt + scol;
      __builtin_amdgcn_global_load_lds((const __attribute__((address_space(1))) void*)gA,
          (__attribute__((address_space(3))) void*)(smA + c*512), 16, 0, 0);
      __builtin_amdgcn_global_load_lds((const __attribute__((address_space(1))) void*)gB,
          (__attribute__((address_space(3))) void*)(smB + c*512), 16, 0, 0);
    }
    __syncthreads();
    #pragma unroll
    for (int ks=0; ks<2; ++ks){
      short8 af[4], bfr[4];
      #pragma unroll
      for (int i=0;i<4;++i){
        af[i]  = *reinterpret_cast<const short8*>(smA + (wm + i*16 + frow)*64 + ks*32 + fk);
        bfr[i] = *reinterpret_cast<const short8*>(smB + (wn + i*16 + frow)*64 + ks*32 + fk);
      }
      #pragma unroll
      for (int mi=0;mi<4;++mi)
        #pragma unroll
        for (int ni=0;ni<4;++ni)
          acc[mi][ni] = __builtin_amdgcn_mfma_f32_16x16x32_bf16(af[mi], bfr[ni], acc[mi][ni], 0, 0, 0);
    }
    __syncthreads();
  }

  const int crow = (lane >> 4) * 4;
  const int ccol = lane & 15;
  #pragma unroll
  for (int mi=0;mi<4;++mi){
    #pragma unroll
    for (int ni=0;ni<4;++ni){
      int col = n0 + wn + ni*16 + ccol;
      if (col < n_limit){
        int row = m0 + wm + mi*16 + crow;
        float badd = bias ? bias[col] : 0.f;
        #pragma unroll
        for (int r=0;r<4;++r){
          size_t off = (size_t)(row + r)*ldc + col;
          float v = acc[mi][ni][r] + badd;
          if (resid) v += resid[off];
          C[off] = v;
        }
      }
    }
  }
}

// ---------------- causal depthwise conv (K=4) + silu ----------------
__global__ void k_conv(const float* __restrict__ zx, const float* __restrict__ cw,
                       const float* __restrict__ cb, float* __restrict__ xc){
  int bl = blockIdx.x;
  int l  = bl & (SEQ-1);
  int c4 = threadIdx.x * 4;               // 576 threads * 4 = 2304 channels
  float4 wv0 = *reinterpret_cast<const float4*>(cw + (c4+0)*4);
  float4 wv1 = *reinterpret_cast<const float4*>(cw + (c4+1)*4);
  float4 wv2 = *reinterpret_cast<const float4*>(cw + (c4+2)*4);
  float4 wv3 = *reinterpret_cast<const float4*>(cw + (c4+3)*4);
  float4 acc = *reinterpret_cast<const float4*>(cb + c4);
  #pragma unroll
  for (int k=0;k<4;++k){
    int li = l - 3 + k;
    if (li >= 0){
      float4 v = *reinterpret_cast<const float4*>(zx + (size_t)(bl - 3 + k)*NPAD1 + DINNER + c4);
      acc.x = fmaf(v.x, ((const float*)&wv0)[k], acc.x);
      acc.y = fmaf(v.y, ((const float*)&wv1)[k], acc.y);
      acc.z = fmaf(v.z, ((const float*)&wv2)[k], acc.z);
      acc.w = fmaf(v.w, ((const float*)&wv3)[k], acc.w);
    }
  }
  acc.x = siluf_(acc.x); acc.y = siluf_(acc.y);
  acc.z = siluf_(acc.z); acc.w = siluf_(acc.w);
  *reinterpret_cast<float4*>(xc + (size_t)bl*CONVDIM + c4) = acc;
}

// ---------------- dt (softplus) and dA ----------------
__global__ __launch_bounds__(256) void k_dt(const float* __restrict__ zx,
                                            const float* __restrict__ dt_bias,
                                            const float* __restrict__ A_log,
                                            float* __restrict__ dtb, float* __restrict__ dab){
  int i = blockIdx.x*256 + threadIdx.x;    // BL*NHEADS
  int h = i & (NHEADS-1);
  int bl = i >> 5;
  float x = zx[(size_t)bl*NPAD1 + DINNER + CONVDIM + h] + dt_bias[h];
  float dt = (x > 20.f) ? x : log1pf(expf(x));
  dtb[i] = dt;
  dab[i] = expf(-dt * expf(A_log[h]));
}

// ---------------- selective scan ----------------
// grid = B*H*4 (p-quarters), 256 thr. thread: p = pq*16 + (tid>>4), n-slice = (tid&15)*8..+8
__global__ __launch_bounds__(256) void k_scan(const float* __restrict__ xc,
                                              const float* __restrict__ dtb,
                                              const float* __restrict__ dab,
                                              const float* __restrict__ Dp,
                                              float* __restrict__ y){
  int bid = blockIdx.x;
  int pq = bid & 3;
  int h  = (bid >> 2) & (NHEADS-1);
  int b  = bid >> 7;
  int tid = threadIdx.x;
  int p  = pq*16 + (tid >> 4);
  int n0 = (tid & 15) * 8;
  float hs[8];
  #pragma unroll
  for (int j=0;j<8;++j) hs[j] = 0.f;
  const float dpv = Dp[h];
  const float* xcb = xc + (size_t)b*SEQ*CONVDIM;
  const float* dtp = dtb + (size_t)b*SEQ*NHEADS + h;
  const float* dap = dab + (size_t)b*SEQ*NHEADS + h;
  float* yb = y + (size_t)b*SEQ*DINNER + h*HEADDIM + p;
  for (int t=0; t<SEQ; ++t){
    const float* xr = xcb + (size_t)t*CONVDIM;
    float dtt = dtp[t*NHEADS];
    float dat = dap[t*NHEADS];
    float xs  = xr[h*HEADDIM + p];
    float4 B0 = *reinterpret_cast<const float4*>(xr + DINNER + n0);
    float4 B1 = *reinterpret_cast<const float4*>(xr + DINNER + n0 + 4);
    float4 C0 = *reinterpret_cast<const float4*>(xr + DINNER + DSTATE + n0);
    float4 C1 = *reinterpret_cast<const float4*>(xr + DINNER + DSTATE + n0 + 4);
    float a = dtt * xs;
    hs[0] = hs[0]*dat + a*B0.x;  hs[1] = hs[1]*dat + a*B0.y;
    hs[2] = hs[2]*dat + a*B0.z;  hs[3] = hs[3]*dat + a*B0.w;
    hs[4] = hs[4]*dat + a*B1.x;  hs[5] = hs[5]*dat + a*B1.y;
    hs[6] = hs[6]*dat + a*B1.z;  hs[7] = hs[7]*dat + a*B1.w;
    float yp = hs[0]*C0.x + hs[1]*C0.y + hs[2]*C0.z + hs[3]*C0.w
             + hs[4]*C1.x + hs[5]*C1.y + hs[6]*C1.z + hs[7]*C1.w;
    yp += __shfl_xor(yp, 1);
    yp += __shfl_xor(yp, 2);
    yp += __shfl_xor(yp, 4);
    yp += __shfl_xor(yp, 8);
    if ((tid & 15) == 0) yb[(size_t)t*DINNER] = yp + dpv*xs;
  }
}

// ---------------- gate (silu(z)) + RMS norm -> bf16 ----------------
__global__ __launch_bounds__(256) void k_gate(const float* __restrict__ y,
                                              const float* __restrict__ zx,
                                              const float* __restrict__ rw,
                                              unsigned short* __restrict__ out){
  int row = blockIdx.x*4 + (threadIdx.x >> 6);
  int lane = threadIdx.x & 63;
  const float* yr = y + (size_t)row*DINNER;
  const float* zr = zx + (size_t)row*NPAD1;
  float4 v[8];
  float s2 = 0.f;
  #pragma unroll
  for (int j=0;j<8;++j){
    int c = (j*64+lane)*4;
    float4 yv = *reinterpret_cast<const float4*>(yr + c);
    float4 zv = *reinterpret_cast<const float4*>(zr + c);
    yv.x *= siluf_(zv.x); yv.y *= siluf_(zv.y);
    yv.z *= siluf_(zv.z); yv.w *= siluf_(zv.w);
    v[j] = yv;
    s2 += yv.x*yv.x + yv.y*yv.y + yv.z*yv.z + yv.w*yv.w;
  }
  #pragma unroll
  for (int o=1;o<64;o<<=1) s2 += __shfl_xor(s2, o);
  float scale = rsqrtf(s2*(1.f/DINNER) + EPSF);
  unsigned short* orow = out + (size_t)row*DINNER;
  #pragma unroll
  for (int j=0;j<8;++j){
    int c = (j*64+lane)*4;
    float4 wv = *reinterpret_cast<const float4*>(rw + c);
    us4 uu;
    uu.x = f2bf(v[j].x*scale*wv.x);
    uu.y = f2bf(v[j].y*scale*wv.y);
    uu.z = f2bf(v[j].z*scale*wv.z);
    uu.w = f2bf(v[j].w*scale*wv.w);
    *reinterpret_cast<us4*>(orow + c) = uu;
  }
}

extern "C" void kernel_launch(void* const* d_in, const int* in_sizes, int n_in,
                              void* d_out, int out_size, void* d_ws, size_t ws_size,
                              hipStream_t stream){
  const int*   tokens  = (const int*)  d_in[0];
  const float* emb     = (const float*)d_in[1];
  const float* ln_w    = (const float*)d_in[2];
  const float* ln_b    = (const float*)d_in[3];
  const float* in_W    = (const float*)d_in[4];
  const float* conv_w  = (const float*)d_in[5];
  const float* conv_b  = (const float*)d_in[6];
  const float* dt_bias = (const float*)d_in[7];
  const float* A_log   = (const float*)d_in[8];
  const float* Dp      = (const float*)d_in[9];
  const float* rms_w   = (const float*)d_in[10];
  const float* out_W   = (const float*)d_in[11];
  const float* lin_W   = (const float*)d_in[12];
  const float* lin_b   = (const float*)d_in[13];
  float* out = (float*)d_out;

  char* ws = (char*)d_ws;
  float* x_res        = (float*)ws;           ws += (size_t)BL*DMODEL*4;     // 33.5 MB
  unsigned short* a_bf = (unsigned short*)ws; ws += (size_t)BL*DINNER*2;     // 33.5 MB
  unsigned short* w_bf = (unsigned short*)ws; ws += (size_t)NPAD1*DMODEL*2;  //  9.2 MB
  float* zx           = (float*)ws;           ws += (size_t)BL*NPAD1*4;      // 146.8 MB
  float* xc           = (float*)ws;           ws += (size_t)BL*CONVDIM*4;    // 75.5 MB
  float* dtb          = (float*)ws;           ws += (size_t)BL*NHEADS*4;
  float* dab          = (float*)ws;           ws += (size_t)BL*NHEADS*4;
  float* yraw         = (float*)ws;           ws += (size_t)BL*DINNER*4;     // 67.1 MB

  k_embed<<<BL, 256, 0, stream>>>(tokens, emb, x_res);

  for (int blk = 0; blk < NBLOCKS; ++blk){
    k_ln<<<BL/4, 256, 0, stream>>>(x_res, ln_w + blk*DMODEL, ln_b + blk*DMODEL, a_bf);

    int t4w = NPAD1*DMODEL/4;
    k_cvt_pad<<<(t4w+255)/256, 256, 0, stream>>>(in_W + (size_t)blk*DINPROJ*DMODEL, w_bf,
                                                 DINPROJ, 10, t4w);
    k_gemm_bt<<<dim3(NPAD1/128, BL/128), 256, 0, stream>>>(a_bf, w_bf, zx,
                                                           nullptr, nullptr,
                                                           DMODEL, NPAD1, NPAD1);

    k_conv<<<BL, CONVDIM/4, 0, stream>>>(zx, conv_w + blk*CONVDIM*4, conv_b + blk*CONVDIM, xc);
    k_dt<<<BL*NHEADS/256, 256, 0, stream>>>(zx, dt_bias + blk*NHEADS, A_log + blk*NHEADS, dtb, dab);
    k_scan<<<BATCH*NHEADS*4, 256, 0, stream>>>(xc, dtb, dab, Dp + blk*NHEADS, yraw);
    k_gate<<<BL/4, 256, 0, stream>>>(yraw, zx, rms_w + blk*DINNER, a_bf);

    int t4o = DMODEL*DINNER/4;
    k_cvt_pad<<<(t4o+255)/256, 256, 0, stream>>>(out_W + (size_t)blk*DMODEL*DINNER, w_bf,
                                                 DMODEL, 11, t4o);
    k_gemm_bt<<<dim3(DMODEL/128, BL/128), 256, 0, stream>>>(a_bf, w_bf, x_res,
                                                            x_res, nullptr,
                                                            DINNER, DMODEL, DMODEL);
  }

  int t4x = BL*DMODEL/4;
  k_cvt_pad<<<(t4x+255)/256, 256, 0, stream>>>(x_res, a_bf, BL, 10, t4x);
  int t4l = 1024*DMODEL/4;
  k_cvt_pad<<<(t4l+255)/256, 256, 0, stream>>>(lin_W, w_bf, NLABEL, 10, t4l);
  k_gemm_bt<<<dim3(1024/128, BL/128), 256, 0, stream>>>(a_bf, w_bf, out,
                                                        nullptr, lin_b,
                                                        DMODEL, NLABEL, NLABEL);
}

// Round 3
// 3236.304 us; speedup vs baseline: 1.8006x; 1.8006x over previous
//
#include <hip/hip_runtime.h>

#define BATCH 4
#define SEQ 2048
#define BL (BATCH*SEQ)          // 8192 rows
#define DMODEL 1024
#define DINNER 2048
#define HEADDIM 64
#define NHEADS 32
#define DSTATE 128
#define CONVDIM 2304            // D_INNER + 2*D_STATE
#define DINPROJ 4384            // 2*D_INNER + 2*D_STATE + NHEADS
#define NPAD1 4480              // DINPROJ padded to multiple of 128
#define NBLOCKS 4
#define NLABEL 1000
#define EPSF 1e-5f

typedef __attribute__((ext_vector_type(8))) short short8;
typedef __attribute__((ext_vector_type(4))) float f32x4;
typedef __attribute__((ext_vector_type(4))) unsigned short us4;

__device__ __forceinline__ unsigned short f2bf(float f){
  unsigned int u = __float_as_uint(f);
  u += 0x7fffu + ((u >> 16) & 1u);   // RNE
  return (unsigned short)(u >> 16);
}
__device__ __forceinline__ unsigned int pack2bf(float a, float b){
  return (unsigned int)f2bf(a) | ((unsigned int)f2bf(b) << 16);
}
__device__ __forceinline__ float siluf_(float x){ return x / (1.f + expf(-x)); }

// ---------------- embedding gather ----------------
__global__ __launch_bounds__(256) void k_embed(const int* __restrict__ tok,
                                               const float* __restrict__ emb,
                                               float* __restrict__ x){
  int i = blockIdx.x*256 + threadIdx.x;
  int row = i >> 8;
  int c4 = (i & 255) << 2;
  float4 v = *reinterpret_cast<const float4*>(emb + (size_t)tok[row]*DMODEL + c4);
  *reinterpret_cast<float4*>(x + (size_t)row*DMODEL + c4) = v;
}

// ---------------- layernorm -> bf16 ----------------
__global__ __launch_bounds__(256) void k_ln(const float* __restrict__ x,
                                            const float* __restrict__ w,
                                            const float* __restrict__ b,
                                            unsigned short* __restrict__ out){
  int row = blockIdx.x*4 + (threadIdx.x >> 6);
  int lane = threadIdx.x & 63;
  const float* xr = x + (size_t)row*DMODEL;
  float4 v[4];
  float s = 0.f;
  #pragma unroll
  for (int j=0;j<4;++j){
    v[j] = *reinterpret_cast<const float4*>(xr + (j*64+lane)*4);
    s += v[j].x + v[j].y + v[j].z + v[j].w;
  }
  #pragma unroll
  for (int o=1;o<64;o<<=1) s += __shfl_xor(s, o);
  float mu = s * (1.f/DMODEL);
  float s2 = 0.f;
  #pragma unroll
  for (int j=0;j<4;++j){
    v[j].x -= mu; v[j].y -= mu; v[j].z -= mu; v[j].w -= mu;
    s2 += v[j].x*v[j].x + v[j].y*v[j].y + v[j].z*v[j].z + v[j].w*v[j].w;
  }
  #pragma unroll
  for (int o=1;o<64;o<<=1) s2 += __shfl_xor(s2, o);
  float rstd = rsqrtf(s2*(1.f/DMODEL) + EPSF);
  unsigned short* orow = out + (size_t)row*DMODEL;
  #pragma unroll
  for (int j=0;j<4;++j){
    int c = (j*64+lane)*4;
    float4 wv = *reinterpret_cast<const float4*>(w + c);
    float4 bv = *reinterpret_cast<const float4*>(b + c);
    us4 uu;
    uu.x = f2bf(v[j].x*rstd*wv.x + bv.x);
    uu.y = f2bf(v[j].y*rstd*wv.y + bv.y);
    uu.z = f2bf(v[j].z*rstd*wv.z + bv.z);
    uu.w = f2bf(v[j].w*rstd*wv.w + bv.w);
    *reinterpret_cast<us4*>(orow + c) = uu;
  }
}

// ---------------- f32 -> bf16 convert with zero row padding ----------------
__global__ __launch_bounds__(256) void k_cvt_pad(const float* __restrict__ src,
                                                 unsigned short* __restrict__ dst,
                                                 int nsrc_rows, int kshift, int total4){
  int i = blockIdx.x*256 + threadIdx.x;
  if (i >= total4) return;
  int e0 = i << 2;
  int row = e0 >> kshift;
  us4 uu;
  if (row < nsrc_rows){
    float4 v = *reinterpret_cast<const float4*>(src + e0);
    uu.x = f2bf(v.x); uu.y = f2bf(v.y); uu.z = f2bf(v.z); uu.w = f2bf(v.w);
  } else {
    uu.x = 0; uu.y = 0; uu.z = 0; uu.w = 0;
  }
  *reinterpret_cast<us4*>(dst + e0) = uu;
}

// ---------------- bf16 GEMM: C[M,N](f32) = A[M,K] * B[N,K]^T (+resid)(+bias) ----------------
__global__ __launch_bounds__(256) void k_gemm_bt(
    const unsigned short* __restrict__ A,
    const unsigned short* __restrict__ B,
    float* __restrict__ C,
    const float* __restrict__ resid,
    const float* __restrict__ bias,
    int K, int ldc, int n_limit)
{
  __shared__ __align__(16) unsigned short smA[128*64];
  __shared__ __align__(16) unsigned short smB[128*64];
  const int tid  = threadIdx.x;
  const int lane = tid & 63;
  const int wave = tid >> 6;
  const int m0 = blockIdx.y * 128;
  const int n0 = blockIdx.x * 128;
  const int wm = (wave >> 1) * 64;
  const int wn = (wave & 1) * 64;
  const int srow = lane >> 3;
  const int scol = (lane & 7) * 8;
  const int frow = lane & 15;
  const int fk   = (lane >> 4) * 8;

  f32x4 acc[4][4];
  #pragma unroll
  for (int i=0;i<4;++i)
    #pragma unroll
    for (int j=0;j<4;++j)
      acc[i][j] = (f32x4){0.f,0.f,0.f,0.f};

  for (int kt = 0; kt < K; kt += 64){
    #pragma unroll
    for (int i=0;i<4;++i){
      int c = wave*4 + i;
      int row = c*8 + srow;
      const unsigned short* gA = A + (size_t)(m0 + row)*K + kt + scol;
      const unsigned short* gB = B + (size_t)(n0 + row)*K + kt + scol;
      __builtin_amdgcn_global_load_lds((const __attribute__((address_space(1))) void*)gA,
          (__attribute__((address_space(3))) void*)(smA + c*512), 16, 0, 0);
      __builtin_amdgcn_global_load_lds((const __attribute__((address_space(1))) void*)gB,
          (__attribute__((address_space(3))) void*)(smB + c*512), 16, 0, 0);
    }
    __syncthreads();
    #pragma unroll
    for (int ks=0; ks<2; ++ks){
      short8 af[4], bfr[4];
      #pragma unroll
      for (int i=0;i<4;++i){
        af[i]  = *reinterpret_cast<const short8*>(smA + (wm + i*16 + frow)*64 + ks*32 + fk);
        bfr[i] = *reinterpret_cast<const short8*>(smB + (wn + i*16 + frow)*64 + ks*32 + fk);
      }
      #pragma unroll
      for (int mi=0;mi<4;++mi)
        #pragma unroll
        for (int ni=0;ni<4;++ni)
          acc[mi][ni] = __builtin_amdgcn_mfma_f32_16x16x32_bf16(af[mi], bfr[ni], acc[mi][ni], 0, 0, 0);
    }
    __syncthreads();
  }

  const int crow = (lane >> 4) * 4;
  const int ccol = lane & 15;
  #pragma unroll
  for (int mi=0;mi<4;++mi){
    #pragma unroll
    for (int ni=0;ni<4;++ni){
      int col = n0 + wn + ni*16 + ccol;
      if (col < n_limit){
        int row = m0 + wm + mi*16 + crow;
        float badd = bias ? bias[col] : 0.f;
        #pragma unroll
        for (int r=0;r<4;++r){
          size_t off = (size_t)(row + r)*ldc + col;
          float v = acc[mi][ni][r] + badd;
          if (resid) v += resid[off];
          C[off] = v;
        }
      }
    }
  }
}

// ---------------- causal depthwise conv (K=4) + silu ----------------
__global__ void k_conv(const float* __restrict__ zx, const float* __restrict__ cw,
                       const float* __restrict__ cb, float* __restrict__ xc){
  int bl = blockIdx.x;
  int l  = bl & (SEQ-1);
  int c4 = threadIdx.x * 4;
  float4 wv0 = *reinterpret_cast<const float4*>(cw + (c4+0)*4);
  float4 wv1 = *reinterpret_cast<const float4*>(cw + (c4+1)*4);
  float4 wv2 = *reinterpret_cast<const float4*>(cw + (c4+2)*4);
  float4 wv3 = *reinterpret_cast<const float4*>(cw + (c4+3)*4);
  float4 acc = *reinterpret_cast<const float4*>(cb + c4);
  #pragma unroll
  for (int k=0;k<4;++k){
    int li = l - 3 + k;
    if (li >= 0){
      float4 v = *reinterpret_cast<const float4*>(zx + (size_t)(bl - 3 + k)*NPAD1 + DINNER + c4);
      acc.x = fmaf(v.x, ((const float*)&wv0)[k], acc.x);
      acc.y = fmaf(v.y, ((const float*)&wv1)[k], acc.y);
      acc.z = fmaf(v.z, ((const float*)&wv2)[k], acc.z);
      acc.w = fmaf(v.w, ((const float*)&wv3)[k], acc.w);
    }
  }
  acc.x = siluf_(acc.x); acc.y = siluf_(acc.y);
  acc.z = siluf_(acc.z); acc.w = siluf_(acc.w);
  *reinterpret_cast<float4*>(xc + (size_t)bl*CONVDIM + c4) = acc;
}

// ---------------- dt (softplus) and log-decay la = -dt*exp(A_log) ----------------
__global__ __launch_bounds__(256) void k_dt(const float* __restrict__ zx,
                                            const float* __restrict__ dt_bias,
                                            const float* __restrict__ A_log,
                                            float* __restrict__ dtb, float* __restrict__ lab){
  int i = blockIdx.x*256 + threadIdx.x;    // BL*NHEADS
  int h = i & (NHEADS-1);
  int bl = i >> 5;
  float x = zx[(size_t)bl*NPAD1 + DINNER + CONVDIM + h] + dt_bias[h];
  float dt = (x > 20.f) ? x : log1pf(expf(x));
  dtb[i] = dt;
  lab[i] = -dt * expf(A_log[h]);
}

// ---------------- SSD chunked scan (Q=64) ----------------
// grid = B*H (128 blocks), 256 threads (4 waves). Wave wq -> (wi=wq>>1, wj=wq&1).
// Per chunk: G = C.B^T (64x64,K=128); P = causal-decay mask(G); Y = cp_i*(C.Hb^T) + P.X;
// H = exp(ls63)*H + sum_j wdt_j x_j B_j  (held in MFMA acc regs, bf16 copy in LDS).
__global__ __launch_bounds__(256) void k_ssd(const float* __restrict__ xc,
                                             const float* __restrict__ dtb,
                                             const float* __restrict__ lab,
                                             float* __restrict__ y){
  __shared__ __align__(16) unsigned short sC[64*136];   // C chunk, [i][n] stride 136
  __shared__ __align__(16) unsigned short sU[128*72];   // union: Bms[64][136] / Ps[64][72] / Bts[128][72]
  __shared__ __align__(16) unsigned short sX[64*72];    // X^T: [p][i] stride 72
  __shared__ __align__(16) unsigned short sH[64*136];   // H^T bf16: [p][n] stride 136
  __shared__ float sLs[64], sCp[64], sWdt[64], sDt[64];

  const int tid  = threadIdx.x;
  const int lane = tid & 63;
  const int wq   = tid >> 6;
  const int wi   = wq >> 1;
  const int wj   = wq & 1;
  const int frow = lane & 15;
  const int fk   = (lane >> 4) * 8;
  const int h    = blockIdx.x & (NHEADS-1);
  const int b    = blockIdx.x >> 5;
  const size_t rowbase = (size_t)b*SEQ;

  for (int e = tid; e < 64*136; e += 256) sH[e] = 0;
  f32x4 hacc[2][4];
  #pragma unroll
  for (int pi=0;pi<2;++pi)
    #pragma unroll
    for (int nj=0;nj<4;++nj)
      hacc[pi][nj] = (f32x4){0.f,0.f,0.f,0.f};
  __syncthreads();

  for (int c = 0; c < SEQ/64; ++c){
    const int t0 = c*64;
    // (a) decay prefix sums (wave 0)
    if (tid < 64){
      size_t idx = (rowbase + t0 + lane)*NHEADS + h;
      float lav = lab[idx];
      float dtv = dtb[idx];
      float ls = lav;
      #pragma unroll
      for (int off=1; off<64; off<<=1){
        float nv = __shfl_up(ls, off);
        if (lane >= off) ls += nv;
      }
      float ls63 = __shfl(ls, 63);
      sLs[lane]  = ls;
      sCp[lane]  = expf(ls);
      sWdt[lane] = expf(ls63 - ls)*dtv;
      sDt[lane]  = dtv;
    }
    __syncthreads();                                    // (b)
    // (c) stage C, Bm(row-major), X^T
    #pragma unroll
    for (int it=0; it<8; ++it){
      int e  = it*256 + tid;          // 2048 float4 slots: 64 rows x 32
      int r  = e >> 5;
      int c4 = (e & 31) * 4;
      const float* src = xc + (rowbase + t0 + r)*CONVDIM;
      float4 vC = *reinterpret_cast<const float4*>(src + DINNER + DSTATE + c4);
      float4 vB = *reinterpret_cast<const float4*>(src + DINNER + c4);
      us4 uC, uB;
      uC.x = f2bf(vC.x); uC.y = f2bf(vC.y); uC.z = f2bf(vC.z); uC.w = f2bf(vC.w);
      uB.x = f2bf(vB.x); uB.y = f2bf(vB.y); uB.z = f2bf(vB.z); uB.w = f2bf(vB.w);
      *reinterpret_cast<us4*>(sC + r*136 + c4) = uC;
      *reinterpret_cast<us4*>(sU + r*136 + c4) = uB;
    }
    #pragma unroll
    for (int it=0; it<8; ++it){
      int e  = it*256 + tid;          // 2048: 32 i-pairs x 64 p (p fast for coalescing)
      int p  = e & 63;
      int i2 = (e >> 6) * 2;
      float v0 = xc[(rowbase + t0 + i2  )*CONVDIM + h*HEADDIM + p];
      float v1 = xc[(rowbase + t0 + i2+1)*CONVDIM + h*HEADDIM + p];
      *reinterpret_cast<unsigned int*>(sX + p*72 + i2) = pack2bf(v0, v1);
    }
    __syncthreads();                                    // (d)
    // (e) G = C.Bm^T
    f32x4 g[2][2];
    #pragma unroll
    for (int mi=0;mi<2;++mi)
      #pragma unroll
      for (int ni=0;ni<2;++ni)
        g[mi][ni] = (f32x4){0.f,0.f,0.f,0.f};
    #pragma unroll
    for (int ks=0; ks<4; ++ks){
      int kb = ks*32 + fk;
      short8 a0 = *reinterpret_cast<const short8*>(sC + (wi*32 +      frow)*136 + kb);
      short8 a1 = *reinterpret_cast<const short8*>(sC + (wi*32 + 16 + frow)*136 + kb);
      short8 b0 = *reinterpret_cast<const short8*>(sU + (wj*32 +      frow)*136 + kb);
      short8 b1 = *reinterpret_cast<const short8*>(sU + (wj*32 + 16 + frow)*136 + kb);
      g[0][0] = __builtin_amdgcn_mfma_f32_16x16x32_bf16(a0,b0,g[0][0],0,0,0);
      g[0][1] = __builtin_amdgcn_mfma_f32_16x16x32_bf16(a0,b1,g[0][1],0,0,0);
      g[1][0] = __builtin_amdgcn_mfma_f32_16x16x32_bf16(a1,b0,g[1][0],0,0,0);
      g[1][1] = __builtin_amdgcn_mfma_f32_16x16x32_bf16(a1,b1,g[1][1],0,0,0);
    }
    __syncthreads();                                    // (f1) all G reads of sU done
    // (e2) P = mask(G) -> sU (stride 72)
    #pragma unroll
    for (int mi=0;mi<2;++mi){
      int ib = wi*32 + mi*16 + (lane>>4)*4;
      #pragma unroll
      for (int ni=0;ni<2;++ni){
        int j = wj*32 + ni*16 + (lane&15);
        float lsj = sLs[j], dtj = sDt[j];
        #pragma unroll
        for (int r=0;r<4;++r){
          int i = ib + r;
          float v = (j <= i) ? expf(sLs[i]-lsj)*dtj*g[mi][ni][r] : 0.f;
          sU[i*72 + j] = f2bf(v);
        }
      }
    }
    __syncthreads();                                    // (f2)
    // (g) Y = cp_i*(C.Hb^T) + P.X
    f32x4 yv[2][2];
    #pragma unroll
    for (int mi=0;mi<2;++mi)
      #pragma unroll
      for (int ni=0;ni<2;++ni)
        yv[mi][ni] = (f32x4){0.f,0.f,0.f,0.f};
    #pragma unroll
    for (int ks=0; ks<4; ++ks){
      int kb = ks*32 + fk;
      short8 a0 = *reinterpret_cast<const short8*>(sC + (wi*32 +      frow)*136 + kb);
      short8 a1 = *reinterpret_cast<const short8*>(sC + (wi*32 + 16 + frow)*136 + kb);
      short8 b0 = *reinterpret_cast<const short8*>(sH + (wj*32 +      frow)*136 + kb);
      short8 b1 = *reinterpret_cast<const short8*>(sH + (wj*32 + 16 + frow)*136 + kb);
      yv[0][0] = __builtin_amdgcn_mfma_f32_16x16x32_bf16(a0,b0,yv[0][0],0,0,0);
      yv[0][1] = __builtin_amdgcn_mfma_f32_16x16x32_bf16(a0,b1,yv[0][1],0,0,0);
      yv[1][0] = __builtin_amdgcn_mfma_f32_16x16x32_bf16(a1,b0,yv[1][0],0,0,0);
      yv[1][1] = __builtin_amdgcn_mfma_f32_16x16x32_bf16(a1,b1,yv[1][1],0,0,0);
    }
    #pragma unroll
    for (int mi=0;mi<2;++mi){
      int ib = wi*32 + mi*16 + (lane>>4)*4;
      #pragma unroll
      for (int r=0;r<4;++r){
        float cpv = sCp[ib + r];
        yv[mi][0][r] *= cpv;
        yv[mi][1][r] *= cpv;
      }
    }
    #pragma unroll
    for (int ks=0; ks<2; ++ks){
      int kb = ks*32 + fk;
      short8 a0 = *reinterpret_cast<const short8*>(sU + (wi*32 +      frow)*72 + kb);
      short8 a1 = *reinterpret_cast<const short8*>(sU + (wi*32 + 16 + frow)*72 + kb);
      short8 b0 = *reinterpret_cast<const short8*>(sX + (wj*32 +      frow)*72 + kb);
      short8 b1 = *reinterpret_cast<const short8*>(sX + (wj*32 + 16 + frow)*72 + kb);
      yv[0][0] = __builtin_amdgcn_mfma_f32_16x16x32_bf16(a0,b0,yv[0][0],0,0,0);
      yv[0][1] = __builtin_amdgcn_mfma_f32_16x16x32_bf16(a0,b1,yv[0][1],0,0,0);
      yv[1][0] = __builtin_amdgcn_mfma_f32_16x16x32_bf16(a1,b0,yv[1][0],0,0,0);
      yv[1][1] = __builtin_amdgcn_mfma_f32_16x16x32_bf16(a1,b1,yv[1][1],0,0,0);
    }
    #pragma unroll
    for (int mi=0;mi<2;++mi){
      int ib = wi*32 + mi*16 + (lane>>4)*4;
      #pragma unroll
      for (int ni=0;ni<2;++ni){
        int p = wj*32 + ni*16 + (lane&15);
        #pragma unroll
        for (int r=0;r<4;++r){
          y[(rowbase + t0 + ib + r)*DINNER + h*HEADDIM + p] = yv[mi][ni][r];
        }
      }
    }
    __syncthreads();                                    // (g2) Ps/Hb/X reads done
    // (h0) stage Bts[n][j] = wdt_j * Bm[j][n]
    #pragma unroll
    for (int it=0; it<16; ++it){
      int e  = it*256 + tid;          // 4096: 32 j-pairs x 128 n (n fast)
      int n  = e & 127;
      int j2 = (e >> 7) * 2;
      float v0 = xc[(rowbase + t0 + j2  )*CONVDIM + DINNER + n] * sWdt[j2];
      float v1 = xc[(rowbase + t0 + j2+1)*CONVDIM + DINNER + n] * sWdt[j2+1];
      *reinterpret_cast<unsigned int*>(sU + n*72 + j2) = pack2bf(v0, v1);
    }
    __syncthreads();                                    // (h1)
    // (h) H update: hacc = cpQ*hacc + X^T-scaled . B
    float cpQ = sCp[63];
    #pragma unroll
    for (int pi=0;pi<2;++pi)
      #pragma unroll
      for (int nj=0;nj<4;++nj)
        hacc[pi][nj] *= cpQ;
    #pragma unroll
    for (int ks=0; ks<2; ++ks){
      int kb = ks*32 + fk;
      short8 a0 = *reinterpret_cast<const short8*>(sX + (wi*32 +      frow)*72 + kb);
      short8 a1 = *reinterpret_cast<const short8*>(sX + (wi*32 + 16 + frow)*72 + kb);
      #pragma unroll
      for (int nj=0;nj<4;++nj){
        short8 bb = *reinterpret_cast<const short8*>(sU + (wj*64 + nj*16 + frow)*72 + kb);
        hacc[0][nj] = __builtin_amdgcn_mfma_f32_16x16x32_bf16(a0,bb,hacc[0][nj],0,0,0);
        hacc[1][nj] = __builtin_amdgcn_mfma_f32_16x16x32_bf16(a1,bb,hacc[1][nj],0,0,0);
      }
    }
    // (j) refresh bf16 H copy
    #pragma unroll
    for (int pi=0;pi<2;++pi){
      int pb = wi*32 + pi*16 + (lane>>4)*4;
      #pragma unroll
      for (int nj=0;nj<4;++nj){
        int n = wj*64 + nj*16 + (lane&15);
        #pragma unroll
        for (int r=0;r<4;++r)
          sH[(pb + r)*136 + n] = f2bf(hacc[pi][nj][r]);
      }
    }
    __syncthreads();                                    // (k)
  }
}

// ---------------- gate: (y + D*x) * silu(z), RMS norm -> bf16 ----------------
__global__ __launch_bounds__(256) void k_gate(const float* __restrict__ y,
                                              const float* __restrict__ zx,
                                              const float* __restrict__ xc,
                                              const float* __restrict__ Dp,
                                              const float* __restrict__ rw,
                                              unsigned short* __restrict__ out){
  int row = blockIdx.x*4 + (threadIdx.x >> 6);
  int lane = threadIdx.x & 63;
  const float* yr = y + (size_t)row*DINNER;
  const float* zr = zx + (size_t)row*NPAD1;
  const float* xr = xc + (size_t)row*CONVDIM;
  float4 v[8];
  float s2 = 0.f;
  #pragma unroll
  for (int j=0;j<8;++j){
    int c = (j*64+lane)*4;
    float4 yv = *reinterpret_cast<const float4*>(yr + c);
    float4 zv = *reinterpret_cast<const float4*>(zr + c);
    float4 xv = *reinterpret_cast<const float4*>(xr + c);
    float dpv = Dp[c >> 6];
    yv.x = (yv.x + dpv*xv.x) * siluf_(zv.x);
    yv.y = (yv.y + dpv*xv.y) * siluf_(zv.y);
    yv.z = (yv.z + dpv*xv.z) * siluf_(zv.z);
    yv.w = (yv.w + dpv*xv.w) * siluf_(zv.w);
    v[j] = yv;
    s2 += yv.x*yv.x + yv.y*yv.y + yv.z*yv.z + yv.w*yv.w;
  }
  #pragma unroll
  for (int o=1;o<64;o<<=1) s2 += __shfl_xor(s2, o);
  float scale = rsqrtf(s2*(1.f/DINNER) + EPSF);
  unsigned short* orow = out + (size_t)row*DINNER;
  #pragma unroll
  for (int j=0;j<8;++j){
    int c = (j*64+lane)*4;
    float4 wv = *reinterpret_cast<const float4*>(rw + c);
    us4 uu;
    uu.x = f2bf(v[j].x*scale*wv.x);
    uu.y = f2bf(v[j].y*scale*wv.y);
    uu.z = f2bf(v[j].z*scale*wv.z);
    uu.w = f2bf(v[j].w*scale*wv.w);
    *reinterpret_cast<us4*>(orow + c) = uu;
  }
}

extern "C" void kernel_launch(void* const* d_in, const int* in_sizes, int n_in,
                              void* d_out, int out_size, void* d_ws, size_t ws_size,
                              hipStream_t stream){
  const int*   tokens  = (const int*)  d_in[0];
  const float* emb     = (const float*)d_in[1];
  const float* ln_w    = (const float*)d_in[2];
  const float* ln_b    = (const float*)d_in[3];
  const float* in_W    = (const float*)d_in[4];
  const float* conv_w  = (const float*)d_in[5];
  const float* conv_b  = (const float*)d_in[6];
  const float* dt_bias = (const float*)d_in[7];
  const float* A_log   = (const float*)d_in[8];
  const float* Dp      = (const float*)d_in[9];
  const float* rms_w   = (const float*)d_in[10];
  const float* out_W   = (const float*)d_in[11];
  const float* lin_W   = (const float*)d_in[12];
  const float* lin_b   = (const float*)d_in[13];
  float* out = (float*)d_out;

  char* ws = (char*)d_ws;
  float* x_res        = (float*)ws;           ws += (size_t)BL*DMODEL*4;
  unsigned short* a_bf = (unsigned short*)ws; ws += (size_t)BL*DINNER*2;
  unsigned short* w_bf = (unsigned short*)ws; ws += (size_t)NPAD1*DMODEL*2;
  float* zx           = (float*)ws;           ws += (size_t)BL*NPAD1*4;
  float* xc           = (float*)ws;           ws += (size_t)BL*CONVDIM*4;
  float* dtb          = (float*)ws;           ws += (size_t)BL*NHEADS*4;
  float* lab          = (float*)ws;           ws += (size_t)BL*NHEADS*4;
  float* yraw         = (float*)ws;           ws += (size_t)BL*DINNER*4;

  k_embed<<<BL, 256, 0, stream>>>(tokens, emb, x_res);

  for (int blk = 0; blk < NBLOCKS; ++blk){
    k_ln<<<BL/4, 256, 0, stream>>>(x_res, ln_w + blk*DMODEL, ln_b + blk*DMODEL, a_bf);

    int t4w = NPAD1*DMODEL/4;
    k_cvt_pad<<<(t4w+255)/256, 256, 0, stream>>>(in_W + (size_t)blk*DINPROJ*DMODEL, w_bf,
                                                 DINPROJ, 10, t4w);
    k_gemm_bt<<<dim3(NPAD1/128, BL/128), 256, 0, stream>>>(a_bf, w_bf, zx,
                                                           nullptr, nullptr,
                                                           DMODEL, NPAD1, NPAD1);

    k_conv<<<BL, CONVDIM/4, 0, stream>>>(zx, conv_w + blk*CONVDIM*4, conv_b + blk*CONVDIM, xc);
    k_dt<<<BL*NHEADS/256, 256, 0, stream>>>(zx, dt_bias + blk*NHEADS, A_log + blk*NHEADS, dtb, lab);
    k_ssd<<<BATCH*NHEADS, 256, 0, stream>>>(xc, dtb, lab, yraw);
    k_gate<<<BL/4, 256, 0, stream>>>(yraw, zx, xc, Dp + blk*NHEADS, rms_w + blk*DINNER, a_bf);

    int t4o = DMODEL*DINNER/4;
    k_cvt_pad<<<(t4o+255)/256, 256, 0, stream>>>(out_W + (size_t)blk*DMODEL*DINNER, w_bf,
                                                 DMODEL, 11, t4o);
    k_gemm_bt<<<dim3(DMODEL/128, BL/128), 256, 0, stream>>>(a_bf, w_bf, x_res,
                                                            x_res, nullptr,
                                                            DINNER, DMODEL, DMODEL);
  }

  int t4x = BL*DMODEL/4;
  k_cvt_pad<<<(t4x+255)/256, 256, 0, stream>>>(x_res, a_bf, BL, 10, t4x);
  int t4l = 1024*DMODEL/4;
  k_cvt_pad<<<(t4l+255)/256, 256, 0, stream>>>(lin_W, w_bf, NLABEL, 10, t4l);
  k_gemm_bt<<<dim3(1024/128, BL/128), 256, 0, stream>>>(a_bf, w_bf, out,
                                                        nullptr, lin_b,
                                                        DMODEL, NLABEL, NLABEL);
}

// Round 4
// 2042.410 us; speedup vs baseline: 2.8531x; 1.5846x over previous
//
#include <hip/hip_runtime.h>

#define BATCH 4
#define SEQ 2048
#define BL (BATCH*SEQ)          // 8192 rows
#define DMODEL 1024
#define DINNER 2048
#define HEADDIM 64
#define NHEADS 32
#define DSTATE 128
#define CONVDIM 2304            // D_INNER + 2*D_STATE
#define DINPROJ 4384            // 2*D_INNER + 2*D_STATE + NHEADS
#define NPAD1 4480              // DINPROJ padded to multiple of 128
#define NBLOCKS 4
#define NLABEL 1000
#define EPSF 1e-5f
#define NSEG 4                  // segments per sequence
#define CSEG 8                  // chunks (of 64) per segment

typedef __attribute__((ext_vector_type(8))) short short8;
typedef __attribute__((ext_vector_type(4))) float f32x4;
typedef __attribute__((ext_vector_type(4))) unsigned short us4;

__device__ __forceinline__ unsigned short f2bf(float f){
  unsigned int u = __float_as_uint(f);
  u += 0x7fffu + ((u >> 16) & 1u);   // RNE
  return (unsigned short)(u >> 16);
}
__device__ __forceinline__ float bf2f(unsigned short u){
  return __uint_as_float((unsigned int)u << 16);
}
__device__ __forceinline__ float siluf_(float x){ return x / (1.f + expf(-x)); }

// ---------------- embedding gather ----------------
__global__ __launch_bounds__(256) void k_embed(const int* __restrict__ tok,
                                               const float* __restrict__ emb,
                                               float* __restrict__ x){
  int i = blockIdx.x*256 + threadIdx.x;
  int row = i >> 8;
  int c4 = (i & 255) << 2;
  float4 v = *reinterpret_cast<const float4*>(emb + (size_t)tok[row]*DMODEL + c4);
  *reinterpret_cast<float4*>(x + (size_t)row*DMODEL + c4) = v;
}

// ---------------- layernorm -> bf16 ----------------
__global__ __launch_bounds__(256) void k_ln(const float* __restrict__ x,
                                            const float* __restrict__ w,
                                            const float* __restrict__ b,
                                            unsigned short* __restrict__ out){
  int row = blockIdx.x*4 + (threadIdx.x >> 6);
  int lane = threadIdx.x & 63;
  const float* xr = x + (size_t)row*DMODEL;
  float4 v[4];
  float s = 0.f;
  #pragma unroll
  for (int j=0;j<4;++j){
    v[j] = *reinterpret_cast<const float4*>(xr + (j*64+lane)*4);
    s += v[j].x + v[j].y + v[j].z + v[j].w;
  }
  #pragma unroll
  for (int o=1;o<64;o<<=1) s += __shfl_xor(s, o);
  float mu = s * (1.f/DMODEL);
  float s2 = 0.f;
  #pragma unroll
  for (int j=0;j<4;++j){
    v[j].x -= mu; v[j].y -= mu; v[j].z -= mu; v[j].w -= mu;
    s2 += v[j].x*v[j].x + v[j].y*v[j].y + v[j].z*v[j].z + v[j].w*v[j].w;
  }
  #pragma unroll
  for (int o=1;o<64;o<<=1) s2 += __shfl_xor(s2, o);
  float rstd = rsqrtf(s2*(1.f/DMODEL) + EPSF);
  unsigned short* orow = out + (size_t)row*DMODEL;
  #pragma unroll
  for (int j=0;j<4;++j){
    int c = (j*64+lane)*4;
    float4 wv = *reinterpret_cast<const float4*>(w + c);
    float4 bv = *reinterpret_cast<const float4*>(b + c);
    us4 uu;
    uu.x = f2bf(v[j].x*rstd*wv.x + bv.x);
    uu.y = f2bf(v[j].y*rstd*wv.y + bv.y);
    uu.z = f2bf(v[j].z*rstd*wv.z + bv.z);
    uu.w = f2bf(v[j].w*rstd*wv.w + bv.w);
    *reinterpret_cast<us4*>(orow + c) = uu;
  }
}

// ---------------- f32 -> bf16 convert with zero row padding ----------------
__global__ __launch_bounds__(256) void k_cvt_pad(const float* __restrict__ src,
                                                 unsigned short* __restrict__ dst,
                                                 int nsrc_rows, int kshift, int total4){
  int i = blockIdx.x*256 + threadIdx.x;
  if (i >= total4) return;
  int e0 = i << 2;
  int row = e0 >> kshift;
  us4 uu;
  if (row < nsrc_rows){
    float4 v = *reinterpret_cast<const float4*>(src + e0);
    uu.x = f2bf(v.x); uu.y = f2bf(v.y); uu.z = f2bf(v.z); uu.w = f2bf(v.w);
  } else {
    uu.x = 0; uu.y = 0; uu.z = 0; uu.w = 0;
  }
  *reinterpret_cast<us4*>(dst + e0) = uu;
}

// ---------------- bf16 GEMM: C[M,N](f32) = A[M,K] * B[N,K]^T (+resid)(+bias) ----------------
__global__ __launch_bounds__(256) void k_gemm_bt(
    const unsigned short* __restrict__ A,
    const unsigned short* __restrict__ B,
    float* __restrict__ C,
    const float* __restrict__ resid,
    const float* __restrict__ bias,
    int K, int ldc, int n_limit)
{
  __shared__ __align__(16) unsigned short smA[128*64];
  __shared__ __align__(16) unsigned short smB[128*64];
  const int tid  = threadIdx.x;
  const int lane = tid & 63;
  const int wave = tid >> 6;
  const int m0 = blockIdx.y * 128;
  const int n0 = blockIdx.x * 128;
  const int wm = (wave >> 1) * 64;
  const int wn = (wave & 1) * 64;
  const int srow = lane >> 3;
  const int scol = (lane & 7) * 8;
  const int frow = lane & 15;
  const int fk   = (lane >> 4) * 8;

  f32x4 acc[4][4];
  #pragma unroll
  for (int i=0;i<4;++i)
    #pragma unroll
    for (int j=0;j<4;++j)
      acc[i][j] = (f32x4){0.f,0.f,0.f,0.f};

  for (int kt = 0; kt < K; kt += 64){
    #pragma unroll
    for (int i=0;i<4;++i){
      int c = wave*4 + i;
      int row = c*8 + srow;
      const unsigned short* gA = A + (size_t)(m0 + row)*K + kt + scol;
      const unsigned short* gB = B + (size_t)(n0 + row)*K + kt + scol;
      __builtin_amdgcn_global_load_lds((const __attribute__((address_space(1))) void*)gA,
          (__attribute__((address_space(3))) void*)(smA + c*512), 16, 0, 0);
      __builtin_amdgcn_global_load_lds((const __attribute__((address_space(1))) void*)gB,
          (__attribute__((address_space(3))) void*)(smB + c*512), 16, 0, 0);
    }
    __syncthreads();
    #pragma unroll
    for (int ks=0; ks<2; ++ks){
      short8 af[4], bfr[4];
      #pragma unroll
      for (int i=0;i<4;++i){
        af[i]  = *reinterpret_cast<const short8*>(smA + (wm + i*16 + frow)*64 + ks*32 + fk);
        bfr[i] = *reinterpret_cast<const short8*>(smB + (wn + i*16 + frow)*64 + ks*32 + fk);
      }
      #pragma unroll
      for (int mi=0;mi<4;++mi)
        #pragma unroll
        for (int ni=0;ni<4;++ni)
          acc[mi][ni] = __builtin_amdgcn_mfma_f32_16x16x32_bf16(af[mi], bfr[ni], acc[mi][ni], 0, 0, 0);
    }
    __syncthreads();
  }

  const int crow = (lane >> 4) * 4;
  const int ccol = lane & 15;
  #pragma unroll
  for (int mi=0;mi<4;++mi){
    #pragma unroll
    for (int ni=0;ni<4;++ni){
      int col = n0 + wn + ni*16 + ccol;
      if (col < n_limit){
        int row = m0 + wm + mi*16 + crow;
        float badd = bias ? bias[col] : 0.f;
        #pragma unroll
        for (int r=0;r<4;++r){
          size_t off = (size_t)(row + r)*ldc + col;
          float v = acc[mi][ni][r] + badd;
          if (resid) v += resid[off];
          C[off] = v;
        }
      }
    }
  }
}

// ---------------- causal depthwise conv (K=4) + silu ----------------
__global__ void k_conv(const float* __restrict__ zx, const float* __restrict__ cw,
                       const float* __restrict__ cb, float* __restrict__ xc){
  int bl = blockIdx.x;
  int l  = bl & (SEQ-1);
  int c4 = threadIdx.x * 4;
  float4 wv0 = *reinterpret_cast<const float4*>(cw + (c4+0)*4);
  float4 wv1 = *reinterpret_cast<const float4*>(cw + (c4+1)*4);
  float4 wv2 = *reinterpret_cast<const float4*>(cw + (c4+2)*4);
  float4 wv3 = *reinterpret_cast<const float4*>(cw + (c4+3)*4);
  float4 acc = *reinterpret_cast<const float4*>(cb + c4);
  #pragma unroll
  for (int k=0;k<4;++k){
    int li = l - 3 + k;
    if (li >= 0){
      float4 v = *reinterpret_cast<const float4*>(zx + (size_t)(bl - 3 + k)*NPAD1 + DINNER + c4);
      acc.x = fmaf(v.x, ((const float*)&wv0)[k], acc.x);
      acc.y = fmaf(v.y, ((const float*)&wv1)[k], acc.y);
      acc.z = fmaf(v.z, ((const float*)&wv2)[k], acc.z);
      acc.w = fmaf(v.w, ((const float*)&wv3)[k], acc.w);
    }
  }
  acc.x = siluf_(acc.x); acc.y = siluf_(acc.y);
  acc.z = siluf_(acc.z); acc.w = siluf_(acc.w);
  *reinterpret_cast<float4*>(xc + (size_t)bl*CONVDIM + c4) = acc;
}

// ---------------- dt (softplus) and log-decay la = -dt*exp(A_log) ----------------
__global__ __launch_bounds__(256) void k_dt(const float* __restrict__ zx,
                                            const float* __restrict__ dt_bias,
                                            const float* __restrict__ A_log,
                                            float* __restrict__ dtb, float* __restrict__ lab){
  int i = blockIdx.x*256 + threadIdx.x;    // BL*NHEADS
  int h = i & (NHEADS-1);
  int bl = i >> 5;
  float x = zx[(size_t)bl*NPAD1 + DINNER + CONVDIM + h] + dt_bias[h];
  float dt = (x > 20.f) ? x : log1pf(expf(x));
  dtb[i] = dt;
  lab[i] = -dt * expf(A_log[h]);
}

// ---------------- SSD chunked scan, segment-parallel ----------------
// grid = B*H*NSEG (512 blocks), 256 threads (4 waves). Each block scans CSEG=8 chunks
// of its segment from zero state. Outputs: y (intra-segment part), csg (per-position
// decay-from-segment-start), hseg (final segment-local state, bf16), dseg (segment
// decay product). Cross-segment contribution added later by k_sscorr.
__global__ __launch_bounds__(256) void k_ssd(const float* __restrict__ xc,
                                             const float* __restrict__ dtb,
                                             const float* __restrict__ lab,
                                             float* __restrict__ y,
                                             float* __restrict__ csg,
                                             unsigned short* __restrict__ hseg,
                                             float* __restrict__ dseg){
  __shared__ __align__(16) unsigned short sC[64*136];   // C chunk, [i][n] stride 136
  __shared__ __align__(16) unsigned short sU[128*72];   // union: Bms[64][136] / Ps[64][72] / Bts[128][72]
  __shared__ __align__(16) unsigned short sX[64*72];    // X^T: [p][i] stride 72
  __shared__ __align__(16) unsigned short sH[64*136];   // H^T bf16: [p][n] stride 136
  __shared__ float sLs[64], sCp[64], sWdt[64], sDt[64];

  const int tid  = threadIdx.x;
  const int lane = tid & 63;
  const int wq   = tid >> 6;
  const int wi   = wq >> 1;
  const int wj   = wq & 1;
  const int frow = lane & 15;
  const int fk   = (lane >> 4) * 8;
  const int s    = blockIdx.x & (NSEG-1);
  const int h    = (blockIdx.x >> 2) & (NHEADS-1);
  const int b    = blockIdx.x >> 7;
  const size_t rowbase = (size_t)b*SEQ;
  const size_t cbase = ((size_t)b*NHEADS + h)*SEQ;

  for (int e = tid; e < 64*136; e += 256) sH[e] = 0;
  f32x4 hacc[2][4];
  #pragma unroll
  for (int pi=0;pi<2;++pi)
    #pragma unroll
    for (int nj=0;nj<4;++nj)
      hacc[pi][nj] = (f32x4){0.f,0.f,0.f,0.f};
  __syncthreads();

  float lsTot = 0.f;   // valid on tid<64 only
  for (int c = s*CSEG; c < s*CSEG + CSEG; ++c){
    const int t0 = c*64;
    // (a) decay prefix sums (wave 0)
    if (tid < 64){
      size_t idx = (rowbase + t0 + lane)*NHEADS + h;
      float lav = lab[idx];
      float dtv = dtb[idx];
      float ls = lav;
      #pragma unroll
      for (int off=1; off<64; off<<=1){
        float nv = __shfl_up(ls, off);
        if (lane >= off) ls += nv;
      }
      csg[cbase + t0 + lane] = expf(lsTot + ls);
      float ls63 = __shfl(ls, 63);
      sLs[lane]  = ls;
      sCp[lane]  = expf(ls);
      sWdt[lane] = expf(ls63 - ls)*dtv;
      sDt[lane]  = dtv;
      lsTot += ls63;
    }
    __syncthreads();                                    // (b)
    // (c) stage C, Bm(row-major)
    #pragma unroll
    for (int it=0; it<8; ++it){
      int e  = it*256 + tid;          // 2048 float4 slots: 64 rows x 32
      int r  = e >> 5;
      int c4 = (e & 31) * 4;
      const float* src = xc + (rowbase + t0 + r)*CONVDIM;
      float4 vC = *reinterpret_cast<const float4*>(src + DINNER + DSTATE + c4);
      float4 vB = *reinterpret_cast<const float4*>(src + DINNER + c4);
      us4 uC, uB;
      uC.x = f2bf(vC.x); uC.y = f2bf(vC.y); uC.z = f2bf(vC.z); uC.w = f2bf(vC.w);
      uB.x = f2bf(vB.x); uB.y = f2bf(vB.y); uB.z = f2bf(vB.z); uB.w = f2bf(vB.w);
      *reinterpret_cast<us4*>(sC + r*136 + c4) = uC;
      *reinterpret_cast<us4*>(sU + r*136 + c4) = uB;
    }
    // (c2) stage X^T [p][i], 8 rows packed per lane -> ds_write_b128 (bank-conflict-free)
    #pragma unroll
    for (int it=0; it<2; ++it){
      int task = it*256 + tid;        // 512 tasks: 64 p x 8 i-blocks
      int p  = task & 63;
      int i0 = (task >> 6) * 8;
      const float* src = xc + (rowbase + t0 + i0)*CONVDIM + h*HEADDIM + p;
      unsigned short tmp[8];
      #pragma unroll
      for (int k=0;k<8;++k)
        tmp[k] = f2bf(src[(size_t)k*CONVDIM]);
      *reinterpret_cast<short8*>(sX + p*72 + i0) = *reinterpret_cast<short8*>(tmp);
    }
    __syncthreads();                                    // (d)
    // (e) G = C.Bm^T
    f32x4 g[2][2];
    #pragma unroll
    for (int mi=0;mi<2;++mi)
      #pragma unroll
      for (int ni=0;ni<2;++ni)
        g[mi][ni] = (f32x4){0.f,0.f,0.f,0.f};
    #pragma unroll
    for (int ks=0; ks<4; ++ks){
      int kb = ks*32 + fk;
      short8 a0 = *reinterpret_cast<const short8*>(sC + (wi*32 +      frow)*136 + kb);
      short8 a1 = *reinterpret_cast<const short8*>(sC + (wi*32 + 16 + frow)*136 + kb);
      short8 b0 = *reinterpret_cast<const short8*>(sU + (wj*32 +      frow)*136 + kb);
      short8 b1 = *reinterpret_cast<const short8*>(sU + (wj*32 + 16 + frow)*136 + kb);
      g[0][0] = __builtin_amdgcn_mfma_f32_16x16x32_bf16(a0,b0,g[0][0],0,0,0);
      g[0][1] = __builtin_amdgcn_mfma_f32_16x16x32_bf16(a0,b1,g[0][1],0,0,0);
      g[1][0] = __builtin_amdgcn_mfma_f32_16x16x32_bf16(a1,b0,g[1][0],0,0,0);
      g[1][1] = __builtin_amdgcn_mfma_f32_16x16x32_bf16(a1,b1,g[1][1],0,0,0);
    }
    __syncthreads();                                    // (f1) all G reads of sU done
    // (e2) P = mask(G) -> sU (stride 72)
    #pragma unroll
    for (int mi=0;mi<2;++mi){
      int ib = wi*32 + mi*16 + (lane>>4)*4;
      #pragma unroll
      for (int ni=0;ni<2;++ni){
        int j = wj*32 + ni*16 + (lane&15);
        float lsj = sLs[j], dtj = sDt[j];
        #pragma unroll
        for (int r=0;r<4;++r){
          int i = ib + r;
          float v = (j <= i) ? expf(sLs[i]-lsj)*dtj*g[mi][ni][r] : 0.f;
          sU[i*72 + j] = f2bf(v);
        }
      }
    }
    __syncthreads();                                    // (f2)
    // (g) Y = cp_i*(C.Hb^T) + P.X
    f32x4 yv[2][2];
    #pragma unroll
    for (int mi=0;mi<2;++mi)
      #pragma unroll
      for (int ni=0;ni<2;++ni)
        yv[mi][ni] = (f32x4){0.f,0.f,0.f,0.f};
    #pragma unroll
    for (int ks=0; ks<4; ++ks){
      int kb = ks*32 + fk;
      short8 a0 = *reinterpret_cast<const short8*>(sC + (wi*32 +      frow)*136 + kb);
      short8 a1 = *reinterpret_cast<const short8*>(sC + (wi*32 + 16 + frow)*136 + kb);
      short8 b0 = *reinterpret_cast<const short8*>(sH + (wj*32 +      frow)*136 + kb);
      short8 b1 = *reinterpret_cast<const short8*>(sH + (wj*32 + 16 + frow)*136 + kb);
      yv[0][0] = __builtin_amdgcn_mfma_f32_16x16x32_bf16(a0,b0,yv[0][0],0,0,0);
      yv[0][1] = __builtin_amdgcn_mfma_f32_16x16x32_bf16(a0,b1,yv[0][1],0,0,0);
      yv[1][0] = __builtin_amdgcn_mfma_f32_16x16x32_bf16(a1,b0,yv[1][0],0,0,0);
      yv[1][1] = __builtin_amdgcn_mfma_f32_16x16x32_bf16(a1,b1,yv[1][1],0,0,0);
    }
    #pragma unroll
    for (int mi=0;mi<2;++mi){
      int ib = wi*32 + mi*16 + (lane>>4)*4;
      #pragma unroll
      for (int r=0;r<4;++r){
        float cpv = sCp[ib + r];
        yv[mi][0][r] *= cpv;
        yv[mi][1][r] *= cpv;
      }
    }
    #pragma unroll
    for (int ks=0; ks<2; ++ks){
      int kb = ks*32 + fk;
      short8 a0 = *reinterpret_cast<const short8*>(sU + (wi*32 +      frow)*72 + kb);
      short8 a1 = *reinterpret_cast<const short8*>(sU + (wi*32 + 16 + frow)*72 + kb);
      short8 b0 = *reinterpret_cast<const short8*>(sX + (wj*32 +      frow)*72 + kb);
      short8 b1 = *reinterpret_cast<const short8*>(sX + (wj*32 + 16 + frow)*72 + kb);
      yv[0][0] = __builtin_amdgcn_mfma_f32_16x16x32_bf16(a0,b0,yv[0][0],0,0,0);
      yv[0][1] = __builtin_amdgcn_mfma_f32_16x16x32_bf16(a0,b1,yv[0][1],0,0,0);
      yv[1][0] = __builtin_amdgcn_mfma_f32_16x16x32_bf16(a1,b0,yv[1][0],0,0,0);
      yv[1][1] = __builtin_amdgcn_mfma_f32_16x16x32_bf16(a1,b1,yv[1][1],0,0,0);
    }
    #pragma unroll
    for (int mi=0;mi<2;++mi){
      int ib = wi*32 + mi*16 + (lane>>4)*4;
      #pragma unroll
      for (int ni=0;ni<2;++ni){
        int p = wj*32 + ni*16 + (lane&15);
        #pragma unroll
        for (int r=0;r<4;++r){
          y[(rowbase + t0 + ib + r)*DINNER + h*HEADDIM + p] = yv[mi][ni][r];
        }
      }
    }
    __syncthreads();                                    // (g2) Ps/Hb/X reads done
    // (h0) stage Bts[n][j] = wdt_j * Bm[j][n], 8 j packed per lane -> b128 writes
    #pragma unroll
    for (int it=0; it<4; ++it){
      int task = it*256 + tid;        // 1024 tasks: 128 n x 8 j-blocks
      int n  = task & 127;
      int j0 = (task >> 7) * 8;
      const float* src = xc + (rowbase + t0 + j0)*CONVDIM + DINNER + n;
      unsigned short tmp[8];
      #pragma unroll
      for (int k=0;k<8;++k)
        tmp[k] = f2bf(src[(size_t)k*CONVDIM] * sWdt[j0+k]);
      *reinterpret_cast<short8*>(sU + n*72 + j0) = *reinterpret_cast<short8*>(tmp);
    }
    __syncthreads();                                    // (h1)
    // (h) H update: hacc = cpQ*hacc + X^T-scaled . B
    float cpQ = sCp[63];
    #pragma unroll
    for (int pi=0;pi<2;++pi)
      #pragma unroll
      for (int nj=0;nj<4;++nj)
        hacc[pi][nj] *= cpQ;
    #pragma unroll
    for (int ks=0; ks<2; ++ks){
      int kb = ks*32 + fk;
      short8 a0 = *reinterpret_cast<const short8*>(sX + (wi*32 +      frow)*72 + kb);
      short8 a1 = *reinterpret_cast<const short8*>(sX + (wi*32 + 16 + frow)*72 + kb);
      #pragma unroll
      for (int nj=0;nj<4;++nj){
        short8 bb = *reinterpret_cast<const short8*>(sU + (wj*64 + nj*16 + frow)*72 + kb);
        hacc[0][nj] = __builtin_amdgcn_mfma_f32_16x16x32_bf16(a0,bb,hacc[0][nj],0,0,0);
        hacc[1][nj] = __builtin_amdgcn_mfma_f32_16x16x32_bf16(a1,bb,hacc[1][nj],0,0,0);
      }
    }
    // (j) refresh bf16 H copy
    #pragma unroll
    for (int pi=0;pi<2;++pi){
      int pb = wi*32 + pi*16 + (lane>>4)*4;
      #pragma unroll
      for (int nj=0;nj<4;++nj){
        int n = wj*64 + nj*16 + (lane&15);
        #pragma unroll
        for (int r=0;r<4;++r)
          sH[(pb + r)*136 + n] = f2bf(hacc[pi][nj][r]);
      }
    }
    __syncthreads();                                    // (k)
  }
  // write segment outputs
  {
    size_t hbase = ((size_t)(b*NHEADS + h)*NSEG + s)*(HEADDIM*DSTATE);
    #pragma unroll
    for (int pi=0;pi<2;++pi){
      int pb = wi*32 + pi*16 + (lane>>4)*4;
      #pragma unroll
      for (int nj=0;nj<4;++nj){
        int n = wj*64 + nj*16 + (lane&15);
        #pragma unroll
        for (int r=0;r<4;++r)
          hseg[hbase + (size_t)(pb + r)*DSTATE + n] = f2bf(hacc[pi][nj][r]);
      }
    }
    if (tid == 0) dseg[(b*NHEADS + h)*NSEG + s] = expf(lsTot);
  }
}

// ---------------- segment-state prefix scan ----------------
// grid = B*H (128), 256 thr. E[1]=Hseg0; E[2]=d1*E[1]+Hseg1; E[3]=d2*E[2]+Hseg2.
__global__ __launch_bounds__(256) void k_segscan(const unsigned short* __restrict__ hseg,
                                                 const float* __restrict__ dseg,
                                                 unsigned short* __restrict__ hpre){
  int bh = blockIdx.x;
  int tid = threadIdx.x;
  const unsigned short* hs = hseg + (size_t)bh*NSEG*8192;
  unsigned short* hp = hpre + (size_t)bh*NSEG*8192;
  float d1 = dseg[bh*NSEG + 1];
  float d2 = dseg[bh*NSEG + 2];
  int off = tid*32;
  #pragma unroll
  for (int v=0; v<4; ++v){
    short8 a0 = *reinterpret_cast<const short8*>(hs +         off + v*8);
    short8 a1 = *reinterpret_cast<const short8*>(hs +  8192 + off + v*8);
    short8 a2 = *reinterpret_cast<const short8*>(hs + 16384 + off + v*8);
    unsigned short e2[8], e3[8];
    #pragma unroll
    for (int j=0;j<8;++j){
      float f1 = bf2f((unsigned short)a0[j]);
      float f2 = d1*f1 + bf2f((unsigned short)a1[j]);
      float f3 = d2*f2 + bf2f((unsigned short)a2[j]);
      e2[j] = f2bf(f2);
      e3[j] = f2bf(f3);
    }
    *reinterpret_cast<short8*>(hp +  8192 + off + v*8) = a0;
    *reinterpret_cast<short8*>(hp + 16384 + off + v*8) = *reinterpret_cast<short8*>(e2);
    *reinterpret_cast<short8*>(hp + 24576 + off + v*8) = *reinterpret_cast<short8*>(e3);
  }
}

// ---------------- cross-segment correction: y += csg_i * (C_i . E[s]^T) ----------------
// grid = B*H*(NSEG-1)*CSEG (3072 blocks), 256 thr (4 waves).
__global__ __launch_bounds__(256) void k_sscorr(const float* __restrict__ xc,
                                                const unsigned short* __restrict__ hpre,
                                                const float* __restrict__ csg,
                                                float* __restrict__ y){
  __shared__ __align__(16) unsigned short sCc[64*136];
  __shared__ __align__(16) unsigned short sHp[64*136];
  const int tid = threadIdx.x;
  const int lane = tid & 63;
  const int wq = tid >> 6;
  const int wi = wq >> 1;
  const int wj = wq & 1;
  const int frow = lane & 15;
  const int fk = (lane >> 4) * 8;
  int bid = blockIdx.x;
  int cis = bid & (CSEG-1);
  int rem = bid >> 3;
  int sm1 = rem % (NSEG-1);
  int bh  = rem / (NSEG-1);
  int s = sm1 + 1;
  int h = bh & (NHEADS-1);
  int b = bh >> 5;
  int t0 = s*(CSEG*64) + cis*64;
  const size_t rowbase = (size_t)b*SEQ;

  // stage C (rows t0..t0+63, bf16)
  #pragma unroll
  for (int it=0; it<8; ++it){
    int e = it*256 + tid;
    int r = e >> 5;
    int c4 = (e & 31) * 4;
    float4 vC = *reinterpret_cast<const float4*>(xc + (rowbase + t0 + r)*CONVDIM + DINNER + DSTATE + c4);
    us4 u;
    u.x = f2bf(vC.x); u.y = f2bf(vC.y); u.z = f2bf(vC.z); u.w = f2bf(vC.w);
    *reinterpret_cast<us4*>(sCc + r*136 + c4) = u;
  }
  // stage Hpre[s] ([p][n] bf16)
  {
    const unsigned short* hsrc = hpre + ((size_t)bh*NSEG + s)*8192 + tid*32;
    int p = tid >> 2;
    int n0 = (tid & 3) * 32;
    #pragma unroll
    for (int v=0; v<4; ++v){
      short8 hv = *reinterpret_cast<const short8*>(hsrc + v*8);
      *reinterpret_cast<short8*>(sHp + p*136 + n0 + v*8) = hv;
    }
  }
  __syncthreads();

  f32x4 cr[2][2];
  #pragma unroll
  for (int mi=0;mi<2;++mi)
    #pragma unroll
    for (int ni=0;ni<2;++ni)
      cr[mi][ni] = (f32x4){0.f,0.f,0.f,0.f};
  #pragma unroll
  for (int ks=0; ks<4; ++ks){
    int kb = ks*32 + fk;
    short8 a0 = *reinterpret_cast<const short8*>(sCc + (wi*32 +      frow)*136 + kb);
    short8 a1 = *reinterpret_cast<const short8*>(sCc + (wi*32 + 16 + frow)*136 + kb);
    short8 b0 = *reinterpret_cast<const short8*>(sHp + (wj*32 +      frow)*136 + kb);
    short8 b1 = *reinterpret_cast<const short8*>(sHp + (wj*32 + 16 + frow)*136 + kb);
    cr[0][0] = __builtin_amdgcn_mfma_f32_16x16x32_bf16(a0,b0,cr[0][0],0,0,0);
    cr[0][1] = __builtin_amdgcn_mfma_f32_16x16x32_bf16(a0,b1,cr[0][1],0,0,0);
    cr[1][0] = __builtin_amdgcn_mfma_f32_16x16x32_bf16(a1,b0,cr[1][0],0,0,0);
    cr[1][1] = __builtin_amdgcn_mfma_f32_16x16x32_bf16(a1,b1,cr[1][1],0,0,0);
  }
  #pragma unroll
  for (int mi=0;mi<2;++mi){
    int ib = wi*32 + mi*16 + (lane>>4)*4;
    #pragma unroll
    for (int ni=0;ni<2;++ni){
      int p = wj*32 + ni*16 + (lane&15);
      #pragma unroll
      for (int r=0;r<4;++r){
        int i = ib + r;
        float cs = csg[(size_t)bh*SEQ + t0 + i];
        float* yp = y + (rowbase + t0 + i)*DINNER + h*HEADDIM + p;
        *yp += cs * cr[mi][ni][r];
      }
    }
  }
}

// ---------------- gate: (y + D*x) * silu(z), RMS norm -> bf16 ----------------
__global__ __launch_bounds__(256) void k_gate(const float* __restrict__ y,
                                              const float* __restrict__ zx,
                                              const float* __restrict__ xc,
                                              const float* __restrict__ Dp,
                                              const float* __restrict__ rw,
                                              unsigned short* __restrict__ out){
  int row = blockIdx.x*4 + (threadIdx.x >> 6);
  int lane = threadIdx.x & 63;
  const float* yr = y + (size_t)row*DINNER;
  const float* zr = zx + (size_t)row*NPAD1;
  const float* xr = xc + (size_t)row*CONVDIM;
  float4 v[8];
  float s2 = 0.f;
  #pragma unroll
  for (int j=0;j<8;++j){
    int c = (j*64+lane)*4;
    float4 yv = *reinterpret_cast<const float4*>(yr + c);
    float4 zv = *reinterpret_cast<const float4*>(zr + c);
    float4 xv = *reinterpret_cast<const float4*>(xr + c);
    float dpv = Dp[c >> 6];
    yv.x = (yv.x + dpv*xv.x) * siluf_(zv.x);
    yv.y = (yv.y + dpv*xv.y) * siluf_(zv.y);
    yv.z = (yv.z + dpv*xv.z) * siluf_(zv.z);
    yv.w = (yv.w + dpv*xv.w) * siluf_(zv.w);
    v[j] = yv;
    s2 += yv.x*yv.x + yv.y*yv.y + yv.z*yv.z + yv.w*yv.w;
  }
  #pragma unroll
  for (int o=1;o<64;o<<=1) s2 += __shfl_xor(s2, o);
  float scale = rsqrtf(s2*(1.f/DINNER) + EPSF);
  unsigned short* orow = out + (size_t)row*DINNER;
  #pragma unroll
  for (int j=0;j<8;++j){
    int c = (j*64+lane)*4;
    float4 wv = *reinterpret_cast<const float4*>(rw + c);
    us4 uu;
    uu.x = f2bf(v[j].x*scale*wv.x);
    uu.y = f2bf(v[j].y*scale*wv.y);
    uu.z = f2bf(v[j].z*scale*wv.z);
    uu.w = f2bf(v[j].w*scale*wv.w);
    *reinterpret_cast<us4*>(orow + c) = uu;
  }
}

extern "C" void kernel_launch(void* const* d_in, const int* in_sizes, int n_in,
                              void* d_out, int out_size, void* d_ws, size_t ws_size,
                              hipStream_t stream){
  const int*   tokens  = (const int*)  d_in[0];
  const float* emb     = (const float*)d_in[1];
  const float* ln_w    = (const float*)d_in[2];
  const float* ln_b    = (const float*)d_in[3];
  const float* in_W    = (const float*)d_in[4];
  const float* conv_w  = (const float*)d_in[5];
  const float* conv_b  = (const float*)d_in[6];
  const float* dt_bias = (const float*)d_in[7];
  const float* A_log   = (const float*)d_in[8];
  const float* Dp      = (const float*)d_in[9];
  const float* rms_w   = (const float*)d_in[10];
  const float* out_W   = (const float*)d_in[11];
  const float* lin_W   = (const float*)d_in[12];
  const float* lin_b   = (const float*)d_in[13];
  float* out = (float*)d_out;

  char* ws = (char*)d_ws;
  float* x_res        = (float*)ws;           ws += (size_t)BL*DMODEL*4;
  unsigned short* a_bf = (unsigned short*)ws; ws += (size_t)BL*DINNER*2;
  unsigned short* w_bf = (unsigned short*)ws; ws += (size_t)NPAD1*DMODEL*2;
  float* zx           = (float*)ws;           ws += (size_t)BL*NPAD1*4;
  float* xc           = (float*)ws;           ws += (size_t)BL*CONVDIM*4;
  float* dtb          = (float*)ws;           ws += (size_t)BL*NHEADS*4;
  float* lab          = (float*)ws;           ws += (size_t)BL*NHEADS*4;
  float* yraw         = (float*)ws;           ws += (size_t)BL*DINNER*4;

  // scan scratch overlays a_bf (dead between in-proj GEMM and k_gate): 17.8 MB < 33.5 MB
  float* csg = (float*)a_bf;                                                 // 1 MB
  unsigned short* hseg = (unsigned short*)(csg + (size_t)BATCH*NHEADS*SEQ);  // 8.4 MB
  unsigned short* hpre = hseg + (size_t)BATCH*NHEADS*NSEG*HEADDIM*DSTATE;    // 8.4 MB
  float* dseg = (float*)(hpre + (size_t)BATCH*NHEADS*NSEG*HEADDIM*DSTATE);   // 2 KB

  k_embed<<<BL, 256, 0, stream>>>(tokens, emb, x_res);

  for (int blk = 0; blk < NBLOCKS; ++blk){
    k_ln<<<BL/4, 256, 0, stream>>>(x_res, ln_w + blk*DMODEL, ln_b + blk*DMODEL, a_bf);

    int t4w = NPAD1*DMODEL/4;
    k_cvt_pad<<<(t4w+255)/256, 256, 0, stream>>>(in_W + (size_t)blk*DINPROJ*DMODEL, w_bf,
                                                 DINPROJ, 10, t4w);
    k_gemm_bt<<<dim3(NPAD1/128, BL/128), 256, 0, stream>>>(a_bf, w_bf, zx,
                                                           nullptr, nullptr,
                                                           DMODEL, NPAD1, NPAD1);

    k_conv<<<BL, CONVDIM/4, 0, stream>>>(zx, conv_w + blk*CONVDIM*4, conv_b + blk*CONVDIM, xc);
    k_dt<<<BL*NHEADS/256, 256, 0, stream>>>(zx, dt_bias + blk*NHEADS, A_log + blk*NHEADS, dtb, lab);
    k_ssd<<<BATCH*NHEADS*NSEG, 256, 0, stream>>>(xc, dtb, lab, yraw, csg, hseg, dseg);
    k_segscan<<<BATCH*NHEADS, 256, 0, stream>>>(hseg, dseg, hpre);
    k_sscorr<<<BATCH*NHEADS*(NSEG-1)*CSEG, 256, 0, stream>>>(xc, hpre, csg, yraw);
    k_gate<<<BL/4, 256, 0, stream>>>(yraw, zx, xc, Dp + blk*NHEADS, rms_w + blk*DINNER, a_bf);

    int t4o = DMODEL*DINNER/4;
    k_cvt_pad<<<(t4o+255)/256, 256, 0, stream>>>(out_W + (size_t)blk*DMODEL*DINNER, w_bf,
                                                 DMODEL, 11, t4o);
    k_gemm_bt<<<dim3(DMODEL/128, BL/128), 256, 0, stream>>>(a_bf, w_bf, x_res,
                                                            x_res, nullptr,
                                                            DINNER, DMODEL, DMODEL);
  }

  int t4x = BL*DMODEL/4;
  k_cvt_pad<<<(t4x+255)/256, 256, 0, stream>>>(x_res, a_bf, BL, 10, t4x);
  int t4l = 1024*DMODEL/4;
  k_cvt_pad<<<(t4l+255)/256, 256, 0, stream>>>(lin_W, w_bf, NLABEL, 10, t4l);
  k_gemm_bt<<<dim3(1024/128, BL/128), 256, 0, stream>>>(a_bf, w_bf, out,
                                                        nullptr, lin_b,
                                                        DMODEL, NLABEL, NLABEL);
}